// Round 5
// baseline (88.257 us; speedup 1.0000x reference)
//
#include <hip/hip_runtime.h>

#define NPTS   1024
#define NGRID  4096
#define NBATCH 16
#define NCH    8
#define TBL    (NBATCH * NPTS * 64)    // 1,048,576 floats per table
#define C2LOG2E -2.8853900817779268f   // -2*log2(e):  exp(-2 d2) = 2^(C*d2)

// ---------------- Kernel 1: separable Gaussian tables ----------------
// E[axis][b][n][i] = exp(-2*(lin_i - X[b][n][axis])^2), axis 0 = rows(gx).
// 2*TBL = 2,097,152 threads; i fastest -> coalesced writes, broadcast X reads.
__global__ __launch_bounds__(256) void rkhs_tables_kernel(
    const float* __restrict__ X, float* __restrict__ E)
{
    const int t    = blockIdx.x * 256 + threadIdx.x;
    const int i    = t & 63;
    const int n    = (t >> 6) & 1023;
    const int b    = (t >> 16) & 15;
    const int axis = t >> 20;                        // 0 or 1
    const float x   = X[(((b << 10) + n) << 1) + axis];
    const float lin = -3.0f + (float)i * (6.0f / 63.0f);
    const float d   = lin - x;
    E[t] = __builtin_amdgcn_exp2f(C2LOG2E * d * d);
}

// ---------------- Kernel 2: main accumulation ----------------
// 512 blocks = (batch 0..15) x (2-row chunk rq 0..31); 512 threads = 8 waves.
// Wave = one 128-n segment (seg via readfirstlane -> n is provably uniform ->
// Ex (dwordx2) and Y (dwordx8) become scalar SMEM loads). lane = col; each
// lane accumulates 2 grid points (rows 2rq, 2rq+1). Only vector load in the
// hot loop: Ey[b][n][lane], 4 B/lane, coalesced, L2-resident.
__global__ __launch_bounds__(512) void rkhs_main_kernel(
    const float* __restrict__ Ex,   // [16][1024][64] (row table)
    const float* __restrict__ Ey,   // [16][1024][64] (col table)
    const float* __restrict__ Y,    // [16][1024][8]
    float* __restrict__ out)        // [grid: 8192][Y_grid: 16*4096*9]
{
    __shared__ float sR[4][128][9];   // 18,432 B partial slots
    __shared__ float sD[128];         // densities

    const int b    = blockIdx.x >> 5;    // 0..15
    const int rq   = blockIdx.x & 31;    // 0..31 -> rows 2rq, 2rq+1
    const int tid  = threadIdx.x;
    const int seg  = __builtin_amdgcn_readfirstlane(tid >> 6);  // 0..7 uniform
    const int lane = tid & 63;           // col

    const float* exp_ = Ex + (size_t)b * (NPTS * 64) + rq * 2;  // + n*64 + {0,1}
    const float* eyp  = Ey + (size_t)b * (NPTS * 64) + lane;    // + n*64
    const float* yp   = Y  + (size_t)b * (NPTS * NCH);          // + n*8

    float dens0 = 0.f, dens1 = 0.f;
    float a0[NCH] = {0.f,0.f,0.f,0.f,0.f,0.f,0.f,0.f};
    float a1[NCH] = {0.f,0.f,0.f,0.f,0.f,0.f,0.f,0.f};

    const int n0 = seg * (NPTS / 8);     // 128-n segment

#pragma unroll 4
    for (int k = 0; k < NPTS / 8; ++k) {
        const int n = n0 + k;
        const float  ey  = eyp[(size_t)n * 64];        // vector, coalesced
        const float  ex0 = exp_[(size_t)n * 64];       // uniform -> SMEM
        const float  ex1 = exp_[(size_t)n * 64 + 1];   // uniform -> SMEM
        const float* y   = yp + (size_t)n * NCH;       // uniform -> SMEM x8

        const float w0 = ex0 * ey;
        const float w1 = ex1 * ey;
        dens0 += w0;
        dens1 += w1;
#pragma unroll
        for (int c = 0; c < NCH; ++c) {
            const float yc = y[c];
            a0[c] = fmaf(w0, yc, a0[c]);
            a1[c] = fmaf(w1, yc, a1[c]);
        }
    }

    // ---- hierarchical cross-segment reduction in 18 KB ----
    float* sRp = &sR[0][0][0];
    if (seg >= 4) {                       // segs 4..7 park in slots 0..3
        float* p0 = sRp + ((seg - 4) * 128 + lane) * 9;
        float* p1 = sRp + ((seg - 4) * 128 + 64 + lane) * 9;
        p0[0] = dens0; p1[0] = dens1;
#pragma unroll
        for (int c = 0; c < NCH; ++c) { p0[1 + c] = a0[c]; p1[1 + c] = a1[c]; }
    }
    __syncthreads();
    if (seg < 4) {                        // merge seg with seg+4
        float* p0 = sRp + (seg * 128 + lane) * 9;
        float* p1 = sRp + (seg * 128 + 64 + lane) * 9;
        dens0 += p0[0]; dens1 += p1[0];
#pragma unroll
        for (int c = 0; c < NCH; ++c) { a0[c] += p0[1 + c]; a1[c] += p1[1 + c]; }
        p0[0] = dens0; p1[0] = dens1;
#pragma unroll
        for (int c = 0; c < NCH; ++c) { p0[1 + c] = a0[c]; p1[1 + c] = a1[c]; }
    }
    __syncthreads();
    if (seg < 2) {                        // merge slot seg with slot seg+2
        float* q0 = sRp + ((seg + 2) * 128 + lane) * 9;
        float* q1 = sRp + ((seg + 2) * 128 + 64 + lane) * 9;
        float* p0 = sRp + (seg * 128 + lane) * 9;
        float* p1 = sRp + (seg * 128 + 64 + lane) * 9;
        dens0 += q0[0]; dens1 += q1[0];
#pragma unroll
        for (int c = 0; c < NCH; ++c) { a0[c] += q0[1 + c]; a1[c] += q1[1 + c]; }
        p0[0] = dens0; p1[0] = dens1;
#pragma unroll
        for (int c = 0; c < NCH; ++c) { p0[1 + c] = a0[c]; p1[1 + c] = a1[c]; }
    }
    __syncthreads();
    // slots 0 + 1 now hold the halves; finish with all 512 threads.

    const float step = 6.0f / 63.0f;
    if (b == 0 && tid < 128) {            // grid coords for this block's rows
        const int r = rq * 2 + (tid >> 6);
        const int c = tid & 63;
        const int m = r * 64 + c;
        out[2 * m]     = -3.0f + (float)r * step;
        out[2 * m + 1] = -3.0f + (float)c * step;
    }

    if (tid < 128) {                      // density per grid point
        const float d = sRp[(0 * 128 + tid) * 9] + sRp[(1 * 128 + tid) * 9];
        sD[tid] = d;
        const int m = (rq * 2 + (tid >> 6)) * 64 + (tid & 63);
        out[(size_t)NGRID * 2 + ((size_t)b * NGRID + m) * 9] = d;
    }
    __syncthreads();

#pragma unroll
    for (int it = 0; it < 2; ++it) {      // 128 gp x 8 ch = 1024 items
        const int idx = tid + it * 512;
        const int gp  = idx >> 3;
        const int c   = (idx & 7) + 1;
        const float f = sRp[(0 * 128 + gp) * 9 + c] + sRp[(1 * 128 + gp) * 9 + c];
        const int m = (rq * 2 + (gp >> 6)) * 64 + (gp & 63);
        out[(size_t)NGRID * 2 + ((size_t)b * NGRID + m) * 9 + c] =
            f / (sD[gp] + 1e-6f);
    }
}

extern "C" void kernel_launch(void* const* d_in, const int* in_sizes, int n_in,
                              void* d_out, int out_size, void* d_ws, size_t ws_size,
                              hipStream_t stream) {
    const float* X = (const float*)d_in[0];   // (16,1024,2) fp32
    const float* Y = (const float*)d_in[1];   // (16,1024,8) fp32
    float* out = (float*)d_out;

    float* E  = (float*)d_ws;                 // 2 tables, 8 MB total
    float* Ex = E;
    float* Ey = E + TBL;

    rkhs_tables_kernel<<<dim3(2 * TBL / 256), dim3(256), 0, stream>>>(X, E);
    rkhs_main_kernel<<<dim3(NBATCH * 32), dim3(512), 0, stream>>>(Ex, Ey, Y, out);
}

// Round 6
// 87.647 us; speedup vs baseline: 1.0070x; 1.0070x over previous
//
#include <hip/hip_runtime.h>

#define NPTS   1024
#define NGRID  4096
#define NBATCH 16
#define NCH    8
#define TBL    (NBATCH * NPTS * 64)     // 1,048,576 floats per table
#define C2LOG2E -2.8853900817779268f    // -2*log2(e): exp(-2 d2) = 2^(C*d2)
#define STEP   (6.0f / 63.0f)

// P partials: [ns=2][b=16][rg=16][ (r*64+c)*9 + ch ]  (2304 floats per slot)
#define PSLOT  2304

// ---------------- Kernel 1: separable Gaussian tables ----------------
// Ey [b][n][c]           (TBL floats)   : exp(-2*(lin_c - Xy)^2)
// ExQ[b][rg][n][rsub]    (TBL floats)   : exp(-2*(lin_{rg*4+rsub} - Xx)^2)
__global__ __launch_bounds__(256) void rkhs_tables_kernel(
    const float* __restrict__ X, float* __restrict__ Ey, float* __restrict__ ExQ)
{
    const int t = blockIdx.x * 256 + threadIdx.x;   // 0 .. 2*TBL-1
    if (t < TBL) {                                  // Ey: c fastest
        const int c = t & 63;
        const int n = (t >> 6) & 1023;
        const int b = t >> 16;
        const float x   = X[(((b << 10) + n) << 1) + 1];
        const float d   = (-3.0f + (float)c * STEP) - x;
        Ey[t] = __builtin_amdgcn_exp2f(C2LOG2E * d * d);
    } else {                                        // ExQ: rsub fastest
        const int u    = t - TBL;
        const int rsub = u & 3;
        const int n    = (u >> 2) & 1023;
        const int rg   = (u >> 12) & 15;
        const int b    = u >> 16;
        const float x   = X[(((b << 10) + n) << 1) + 0];
        const float d   = (-3.0f + (float)(rg * 4 + rsub) * STEP) - x;
        ExQ[u] = __builtin_amdgcn_exp2f(C2LOG2E * d * d);
    }
}

// ---------------- Kernel 2: main accumulation ----------------
// 512 blocks = (b 0..15) x (rg 0..15) x (ns 0..1); 512 threads = 8 waves.
// wave = 64-n segment of the block's 512-n half; lane = col c.
// Per iter: ex4 (b128 broadcast) + y (2x b128 broadcast) from LDS,
// ey coalesced 4B/lane from global (L2). 4 rows x 9 accumulators per lane.
__global__ __launch_bounds__(512, 4) void rkhs_main_kernel(
    const float* __restrict__ ExQ,  // [16][16][1024][4]
    const float* __restrict__ Ey,   // [16][1024][64]
    const float* __restrict__ Y,    // [16][1024][8]
    float* __restrict__ P)          // [2][16][16][2304]
{
    __shared__ float smem[9216];    // 36 KB: staging (24 KB) then reduction

    const int b    = blockIdx.x >> 5;
    const int rg   = (blockIdx.x >> 1) & 15;
    const int ns   = blockIdx.x & 1;
    const int tid  = threadIdx.x;
    const int seg  = tid >> 6;      // 0..7
    const int lane = tid & 63;      // col

    float4* sExT4 = (float4*)smem;            // [512 n][4 r]   (8 KB)
    float4* sY4   = (float4*)(smem + 2048);   // [512 n][8 ch]  (16 KB)

    // ---- stage ExQ-half and Y-half (float4, coalesced) ----
    {
        const float4* g = (const float4*)(ExQ + (((size_t)b * 16 + rg) * 1024 + ns * 512) * 4);
        sExT4[tid] = g[tid];                              // 512 f4
        const float4* gy = (const float4*)(Y + ((size_t)b * 1024 + ns * 512) * 8);
        sY4[tid]       = gy[tid];                         // 1024 f4
        sY4[tid + 512] = gy[tid + 512];
    }
    __syncthreads();

    const float* eyp = Ey + (size_t)b * (NPTS * 64) + ((size_t)ns * 512 + seg * 64) * 64 + lane;

    float dens[4] = {0.f, 0.f, 0.f, 0.f};
    float a0[NCH] = {0.f,0.f,0.f,0.f,0.f,0.f,0.f,0.f};
    float a1[NCH] = {0.f,0.f,0.f,0.f,0.f,0.f,0.f,0.f};
    float a2[NCH] = {0.f,0.f,0.f,0.f,0.f,0.f,0.f,0.f};
    float a3[NCH] = {0.f,0.f,0.f,0.f,0.f,0.f,0.f,0.f};

    const int nl0 = seg * 64;
#pragma unroll 4
    for (int k = 0; k < 64; ++k) {
        const int nl = nl0 + k;
        const float4 ex4 = sExT4[nl];         // broadcast b128
        const float4 y0  = sY4[2 * nl];       // broadcast b128
        const float4 y1  = sY4[2 * nl + 1];
        const float  ey  = eyp[(size_t)k * 64];  // coalesced global (L2)

        const float w0 = ex4.x * ey;
        const float w1 = ex4.y * ey;
        const float w2 = ex4.z * ey;
        const float w3 = ex4.w * ey;
        dens[0] += w0; dens[1] += w1; dens[2] += w2; dens[3] += w3;

        a0[0]=fmaf(w0,y0.x,a0[0]); a0[1]=fmaf(w0,y0.y,a0[1]); a0[2]=fmaf(w0,y0.z,a0[2]); a0[3]=fmaf(w0,y0.w,a0[3]);
        a0[4]=fmaf(w0,y1.x,a0[4]); a0[5]=fmaf(w0,y1.y,a0[5]); a0[6]=fmaf(w0,y1.z,a0[6]); a0[7]=fmaf(w0,y1.w,a0[7]);
        a1[0]=fmaf(w1,y0.x,a1[0]); a1[1]=fmaf(w1,y0.y,a1[1]); a1[2]=fmaf(w1,y0.z,a1[2]); a1[3]=fmaf(w1,y0.w,a1[3]);
        a1[4]=fmaf(w1,y1.x,a1[4]); a1[5]=fmaf(w1,y1.y,a1[5]); a1[6]=fmaf(w1,y1.z,a1[6]); a1[7]=fmaf(w1,y1.w,a1[7]);
        a2[0]=fmaf(w2,y0.x,a2[0]); a2[1]=fmaf(w2,y0.y,a2[1]); a2[2]=fmaf(w2,y0.z,a2[2]); a2[3]=fmaf(w2,y0.w,a2[3]);
        a2[4]=fmaf(w2,y1.x,a2[4]); a2[5]=fmaf(w2,y1.y,a2[5]); a2[6]=fmaf(w2,y1.z,a2[6]); a2[7]=fmaf(w2,y1.w,a2[7]);
        a3[0]=fmaf(w3,y0.x,a3[0]); a3[1]=fmaf(w3,y0.y,a3[1]); a3[2]=fmaf(w3,y0.z,a3[2]); a3[3]=fmaf(w3,y0.w,a3[3]);
        a3[4]=fmaf(w3,y1.x,a3[4]); a3[5]=fmaf(w3,y1.y,a3[5]); a3[6]=fmaf(w3,y1.z,a3[6]); a3[7]=fmaf(w3,y1.w,a3[7]);
    }
    __syncthreads();                 // staging region now dead

    // ---- 8-seg -> 1 reduction using 4 slots of 2304 floats ----
    float* sRed = smem;
    float* ar[4] = {a0, a1, a2, a3};

#define PARK(slot)                                                        \
    { float* p = sRed + (slot) * PSLOT;                                   \
      for (int r = 0; r < 4; ++r) {                                       \
          float* q = p + (r * 64 + lane) * 9;                             \
          q[0] = dens[r];                                                 \
          for (int ch = 0; ch < NCH; ++ch) q[1 + ch] = ar[r][ch]; } }
#define ABSORB(slot)                                                      \
    { float* p = sRed + (slot) * PSLOT;                                   \
      for (int r = 0; r < 4; ++r) {                                       \
          float* q = p + (r * 64 + lane) * 9;                             \
          dens[r] += q[0];                                                \
          for (int ch = 0; ch < NCH; ++ch) ar[r][ch] += q[1 + ch]; } }

    if (seg >= 4) PARK(seg - 4)
    __syncthreads();
    if (seg < 4)  ABSORB(seg)
    __syncthreads();
    if (seg == 2 || seg == 3) PARK(seg - 2)
    __syncthreads();
    if (seg < 2)  ABSORB(seg)
    __syncthreads();
    if (seg == 1) PARK(0)
    __syncthreads();
    if (seg == 0) {
        ABSORB(0)
        float* p = P + (((size_t)ns * 16 + b) * 16 + rg) * PSLOT;
#pragma unroll
        for (int r = 0; r < 4; ++r) {
            float* q = p + (r * 64 + lane) * 9;
            q[0] = dens[r];
#pragma unroll
            for (int ch = 0; ch < NCH; ++ch) q[1 + ch] = ar[r][ch];
        }
    }
#undef PARK
#undef ABSORB
}

// ---------------- Kernel 3: combine halves + normalize ----------------
// 65536 threads = (b, gp). Reads both ns partials, writes 9 floats.
__global__ __launch_bounds__(256) void rkhs_final_kernel(
    const float* __restrict__ P, float* __restrict__ out)
{
    const int t  = blockIdx.x * 256 + threadIdx.x;   // 0..65535
    const int b  = t >> 12;
    const int gp = t & 4095;
    const int rg = gp >> 8;
    const int off = ((gp & 255) * 9);                // (r*64+c)*9 within slot

    const float* p0 = P + (((size_t)0 * 16 + b) * 16 + rg) * PSLOT + off;
    const float* p1 = P + (((size_t)1 * 16 + b) * 16 + rg) * PSLOT + off;

    if (b == 0) {
        out[2 * gp]     = -3.0f + (float)(gp >> 6) * STEP;
        out[2 * gp + 1] = -3.0f + (float)(gp & 63) * STEP;
    }

    const float dens = p0[0] + p1[0];
    const float inv  = 1.0f / (dens + 1e-6f);
    float* o = out + (size_t)NGRID * 2 + ((size_t)b * NGRID + gp) * 9;
    o[0] = dens;
#pragma unroll
    for (int ch = 1; ch < 9; ++ch)
        o[ch] = (p0[ch] + p1[ch]) * inv;
}

extern "C" void kernel_launch(void* const* d_in, const int* in_sizes, int n_in,
                              void* d_out, int out_size, void* d_ws, size_t ws_size,
                              hipStream_t stream) {
    const float* X = (const float*)d_in[0];   // (16,1024,2) fp32
    const float* Y = (const float*)d_in[1];   // (16,1024,8) fp32
    float* out = (float*)d_out;

    float* Ey  = (float*)d_ws;                // TBL floats
    float* ExQ = Ey + TBL;                    // TBL floats
    float* P   = ExQ + TBL;                   // 2*16*16*2304 floats (4.7 MB)

    rkhs_tables_kernel<<<dim3(2 * TBL / 256), dim3(256), 0, stream>>>(X, Ey, ExQ);
    rkhs_main_kernel<<<dim3(512), dim3(512), 0, stream>>>(ExQ, Ey, Y, P);
    rkhs_final_kernel<<<dim3(256), dim3(256), 0, stream>>>(P, out);
}

// Round 7
// 79.125 us; speedup vs baseline: 1.1154x; 1.1077x over previous
//
#include <hip/hip_runtime.h>

#define NCH   8
#define STEP  (6.0f / 63.0f)
#define SCAL  1.69864636f          // sqrt(2*log2(e)); exp(-2 d^2) = 2^(-(S d)^2)
#define PSLOT 4608                 // 8 r x 64 c x 9 ch floats per block partial

// grid: 512 blocks = b(16) x rg(8) x nq(4); block 256 thr = 4 waves.
// Block: rows [rg*8, rg*8+8), all 64 cols, n in [nq*256, nq*256+256).
// Wave w handles n-sub [w*64, w*64+64). lane = col.
// Hot loop: ex8 + y8 + S*Xy from LDS (uniform -> broadcast, no conflicts),
// ey computed in-register (no LDS, no global). 72 accumulators/lane.
__global__ __launch_bounds__(256, 2) void rkhs_main(
    const float* __restrict__ X,   // (16,1024,2)
    const float* __restrict__ Y,   // (16,1024,8)
    float* __restrict__ P)         // [512][4608] partials
{
    __shared__ float smem[2 * PSLOT];      // 36 KB (staging aliases front)
    float* sEx = smem;                     // [256 n][8 r]
    float* sY  = smem + 2048;              // [256 n][8 ch]
    float* sXy = smem + 4096;              // [256 n] : S*Xy

    const int b    = blockIdx.x >> 5;
    const int rg   = (blockIdx.x >> 2) & 7;
    const int nq   = blockIdx.x & 3;
    const int tid  = threadIdx.x;
    const int wave = tid >> 6;
    const int lane = tid & 63;
    const int n0   = nq * 256;
    const int r0   = rg * 8;

    // ---- staging: thread tid owns n = tid ----
    {
        const float2 xn = ((const float2*)X)[b * 1024 + n0 + tid];
        sXy[tid] = SCAL * xn.y;
        const float sx = SCAL * xn.x;
        float4 ee[2];
#pragma unroll
        for (int r = 0; r < 8; ++r) {
            const float d = SCAL * (-3.0f + (float)(r0 + r) * STEP) - sx;
            ((float*)ee)[r] = __builtin_amdgcn_exp2f(-(d * d));
        }
        ((float4*)sEx)[tid * 2]     = ee[0];
        ((float4*)sEx)[tid * 2 + 1] = ee[1];

        const float4* Yg = (const float4*)(Y + ((size_t)b * 1024 + n0) * 8);
        ((float4*)sY)[tid]       = Yg[tid];
        ((float4*)sY)[tid + 256] = Yg[tid + 256];
    }
    __syncthreads();

    const float gyS = SCAL * (-3.0f + (float)lane * STEP);
    float dens[8] = {0.f,0.f,0.f,0.f,0.f,0.f,0.f,0.f};
    float a[8][8];
#pragma unroll
    for (int r = 0; r < 8; ++r)
#pragma unroll
        for (int c = 0; c < 8; ++c) a[r][c] = 0.f;

    const float4* sEx4 = (const float4*)sEx;
    const float4* sY4  = (const float4*)sY;
    const int kb = wave * 64;

#pragma unroll 4
    for (int k = 0; k < 64; ++k) {
        const int n = kb + k;
        const float dy = gyS - sXy[n];                  // b32 broadcast
        const float ey = __builtin_amdgcn_exp2f(-(dy * dy));
        const float4 e0 = sEx4[2 * n];                  // b128 broadcast x2
        const float4 e1 = sEx4[2 * n + 1];
        const float4 y0 = sY4[2 * n];                   // b128 broadcast x2
        const float4 y1 = sY4[2 * n + 1];
        const float w[8] = {e0.x * ey, e0.y * ey, e0.z * ey, e0.w * ey,
                            e1.x * ey, e1.y * ey, e1.z * ey, e1.w * ey};
#pragma unroll
        for (int r = 0; r < 8; ++r) {
            dens[r] += w[r];
            a[r][0] = fmaf(w[r], y0.x, a[r][0]);
            a[r][1] = fmaf(w[r], y0.y, a[r][1]);
            a[r][2] = fmaf(w[r], y0.z, a[r][2]);
            a[r][3] = fmaf(w[r], y0.w, a[r][3]);
            a[r][4] = fmaf(w[r], y1.x, a[r][4]);
            a[r][5] = fmaf(w[r], y1.y, a[r][5]);
            a[r][6] = fmaf(w[r], y1.z, a[r][6]);
            a[r][7] = fmaf(w[r], y1.w, a[r][7]);
        }
    }
    __syncthreads();                 // staging dead; reuse as 2 slots

    float* slot0 = smem;
    float* slot1 = smem + PSLOT;

#define PARK(S_)                                                         \
    {                                                                    \
        _Pragma("unroll") for (int r = 0; r < 8; ++r) {                  \
            float* q = (S_) + (r * 64 + lane) * 9;                       \
            q[0] = dens[r];                                              \
            _Pragma("unroll") for (int c = 0; c < 8; ++c) q[1+c] = a[r][c]; \
        }                                                                \
    }
#define ABSORB(S_)                                                       \
    {                                                                    \
        _Pragma("unroll") for (int r = 0; r < 8; ++r) {                  \
            const float* q = (S_) + (r * 64 + lane) * 9;                 \
            dens[r] += q[0];                                             \
            _Pragma("unroll") for (int c = 0; c < 8; ++c) a[r][c] += q[1+c]; \
        }                                                                \
    }

    if (wave == 2) PARK(slot0)
    if (wave == 3) PARK(slot1)
    __syncthreads();
    if (wave == 0) ABSORB(slot0)
    if (wave == 1) ABSORB(slot1)
    __syncthreads();
    if (wave == 1) PARK(slot1)
    __syncthreads();
    if (wave == 0) { ABSORB(slot1) PARK(slot0) }
    __syncthreads();
#undef PARK
#undef ABSORB

    // coalesced copy of the block partial (4608 floats) to global
    float* p = P + (size_t)blockIdx.x * PSLOT;
#pragma unroll
    for (int i = 0; i < 18; ++i)
        p[i * 256 + tid] = smem[i * 256 + tid];
}

// ---- combine the 4 nq partials + normalize; 65536 threads = (b, gp) ----
__global__ __launch_bounds__(256) void rkhs_final(
    const float* __restrict__ P, float* __restrict__ out)
{
    const int t  = blockIdx.x * 256 + threadIdx.x;   // 0..65535
    const int b  = t >> 12;
    const int gp = t & 4095;             // row*64 + col
    const int rg = gp >> 9;              // (row>>3)
    const int within = gp & 511;         // (row&7)*64 + col

    const float* p0 = P + ((size_t)(b * 8 + rg) * 4) * PSLOT + (size_t)within * 9;
    float v[9];
#pragma unroll
    for (int c = 0; c < 9; ++c) v[c] = p0[c];
#pragma unroll
    for (int q = 1; q < 4; ++q) {
        const float* pq = p0 + (size_t)q * PSLOT;
#pragma unroll
        for (int c = 0; c < 9; ++c) v[c] += pq[c];
    }

    if (b == 0) {
        out[2 * gp]     = -3.0f + (float)(gp >> 6) * STEP;
        out[2 * gp + 1] = -3.0f + (float)(gp & 63) * STEP;
    }

    float* o = out + 8192 + (size_t)t * 9;
    const float inv = 1.0f / (v[0] + 1e-6f);
    o[0] = v[0];
#pragma unroll
    for (int c = 1; c < 9; ++c) o[c] = v[c] * inv;
}

extern "C" void kernel_launch(void* const* d_in, const int* in_sizes, int n_in,
                              void* d_out, int out_size, void* d_ws, size_t ws_size,
                              hipStream_t stream) {
    const float* X = (const float*)d_in[0];   // (16,1024,2) fp32
    const float* Y = (const float*)d_in[1];   // (16,1024,8) fp32
    float* out = (float*)d_out;
    float* P   = (float*)d_ws;                // 512*4608 floats = 9.4 MB

    rkhs_main <<<dim3(512), dim3(256), 0, stream>>>(X, Y, P);
    rkhs_final<<<dim3(256), dim3(256), 0, stream>>>(P, out);
}

// Round 8
// 77.300 us; speedup vs baseline: 1.1418x; 1.0236x over previous
//
#include <hip/hip_runtime.h>

typedef _Float16 half8  __attribute__((ext_vector_type(8)));
typedef float    floatx4 __attribute__((ext_vector_type(4)));

#define STEP  (6.0f / 63.0f)
#define SCAL  1.69864636f     // sqrt(2*log2(e)):  exp(-2 d^2) = 2^(-(S d)^2)
#define KCH   256             // k-chunk staged per round
#define LSTR  264             // padded LDS row stride (f16): uniform bank spread

// ws layout:
//   ExT: [16][64][1024] f16  @ 0      (2 MB)   exp table, rows
//   EyT: [16][64][1024] f16  @ 2 MB   (2 MB)   exp table, cols
//   YbT: [16][16][1024] f16  @ 4 MB   (512 KB) [ones, Y^T, zero-pad]
//   P  : [512][4096]    f32  @ 8 MB   (8 MB)   per-block partials

// ---------------- Kernel 1: f16 tables (2M exps, not 67M) ----------------
__global__ __launch_bounds__(256) void rkhs_tables(
    const float* __restrict__ X, const float* __restrict__ Y,
    _Float16* __restrict__ ExT, _Float16* __restrict__ EyT,
    _Float16* __restrict__ YbT)
{
    const int gid = blockIdx.x * 256 + threadIdx.x;
    if (gid < 262144) {                     // Ex/Ey: 2 x 16 x 64 x 128 chunks
        const int kc = gid & 127;
        const int r  = (gid >> 7) & 63;
        const int b  = (gid >> 13) & 15;
        const int ax = gid >> 17;           // 0 = Ex (rows/x), 1 = Ey (cols/y)
        const float gs = SCAL * (-3.0f + (float)r * STEP);
        half8 hv;
#pragma unroll
        for (int j = 0; j < 8; ++j) {
            const int k = kc * 8 + j;
            const float x = X[(((b << 10) + k) << 1) + ax];
            const float d = gs - SCAL * x;
            hv[j] = (_Float16)__builtin_amdgcn_exp2f(-(d * d));
        }
        _Float16* dst = (ax ? EyT : ExT) + ((size_t)((b << 6) + r) << 10) + kc * 8;
        *(half8*)dst = hv;
    } else {                                // YbT: 16 x 16 x 128 chunks
        const int gid2 = gid - 262144;
        const int kc = gid2 & 127;
        const int n  = (gid2 >> 7) & 15;
        const int b  = gid2 >> 11;
        half8 hv;
#pragma unroll
        for (int j = 0; j < 8; ++j) {
            const int k = kc * 8 + j;
            float v = 0.0f;
            if (n == 0) v = 1.0f;
            else if (n <= 8) v = Y[(((b << 10) + k) << 3) + n - 1];
            hv[j] = (_Float16)v;
        }
        *(half8*)(YbT + ((size_t)((b << 4) + n) << 10) + kc * 8) = hv;
    }
}

// ---------------- Kernel 2: MFMA GEMM ----------------
// 512 blocks = b(16) x rq(16: 4-row group) x kh(2: 512-k half); 256 thr = 4 waves.
// Wave w = row rq*4+w; covers 4 col-tiles of 16 x 16(ch) x k.
// A-frag = Ex-frag * Ey-frag via v_pk_mul_f16 (layouts per m89/m91/m118-120).
__global__ __launch_bounds__(256, 2) void rkhs_gemm(
    const _Float16* __restrict__ ExT, const _Float16* __restrict__ EyT,
    const _Float16* __restrict__ YbT, float* __restrict__ P)
{
    __shared__ _Float16 sEy[64 * LSTR];   // 33,792 B
    __shared__ _Float16 sEx[4 * LSTR];    //  2,112 B
    __shared__ _Float16 sYb[16 * LSTR];   //  8,448 B

    const int b   = blockIdx.x >> 5;
    const int rq  = (blockIdx.x >> 1) & 15;
    const int kh  = blockIdx.x & 1;
    const int tid = threadIdx.x;
    const int w   = tid >> 6;
    const int l   = tid & 63;
    const int q   = l >> 4;     // quad
    const int n   = l & 15;

    floatx4 acc[4];
#pragma unroll
    for (int ct = 0; ct < 4; ++ct) acc[ct] = (floatx4){0.f, 0.f, 0.f, 0.f};

    for (int ch = 0; ch < 2; ++ch) {
        const int kbase = kh * 512 + ch * KCH;
        __syncthreads();                     // LDS reuse guard between chunks
        {   // stage Ey: 64 rows x 256 f16; 4 threads/row, 8 x 16B each
            const int c  = tid >> 2;
            const int sg = tid & 3;
            const _Float16* g = EyT + ((size_t)((b << 6) + c) << 10) + kbase + sg * 64;
            _Float16* s = sEy + c * LSTR + sg * 64;
#pragma unroll
            for (int j = 0; j < 8; ++j)
                *(half8*)(s + j * 8) = *(const half8*)(g + j * 8);
        }
        if (tid < 128) {   // stage Ex rows rq*4..+3: 4 x 32 chunks
            const int rr = tid >> 5, cc = tid & 31;
            *(half8*)(sEx + rr * LSTR + cc * 8) =
                *(const half8*)(ExT + ((size_t)((b << 6) + rq * 4 + rr) << 10) + kbase + cc * 8);
        }
        {   // stage YbT: 16 x 32 chunks, 2/thread
            const int nn = tid >> 4, cc = tid & 15;
#pragma unroll
            for (int h = 0; h < 2; ++h)
                *(half8*)(sYb + nn * LSTR + (cc + 16 * h) * 8) =
                    *(const half8*)(YbT + ((size_t)((b << 4) + nn) << 10) + kbase + (cc + 16 * h) * 8);
        }
        __syncthreads();

        const _Float16* exr = sEx + w * LSTR + q * 8;
        const _Float16* ybr = sYb + n * LSTR + q * 8;
        const _Float16* eyr = sEy + n * LSTR + q * 8;

#pragma unroll
        for (int s = 0; s < KCH / 32; ++s) {          // 8 k-steps
            const int k0 = s * 32;
            const half8 aex = *(const half8*)(exr + k0);           // b128
            const half8 byb = *(const half8*)(ybr + k0);           // b128
#pragma unroll
            for (int ct = 0; ct < 4; ++ct) {
                const half8 ey = *(const half8*)(eyr + ct * 16 * LSTR + k0);
                const half8 a  = aex * ey;            // 4x v_pk_mul_f16
                acc[ct] = __builtin_amdgcn_mfma_f32_16x16x32_f16(a, byb, acc[ct], 0, 0, 0);
            }
        }
    }

    // partials: P[blk][w][grid-col][16ch];  D: m=(q*4+i) within tile, n=ch
    float* pb = P + ((size_t)blockIdx.x << 12) + (w << 10);
#pragma unroll
    for (int ct = 0; ct < 4; ++ct)
#pragma unroll
        for (int i = 0; i < 4; ++i)
            pb[(ct * 16 + q * 4 + i) * 16 + n] = acc[ct][i];
}

// ---------------- Kernel 3: combine k-halves + normalize ----------------
__global__ __launch_bounds__(256) void rkhs_final(
    const float* __restrict__ P, float* __restrict__ out)
{
    const int t   = blockIdx.x * 256 + threadIdx.x;   // 0..65535 = (b, gp)
    const int b   = t >> 12;
    const int gp  = t & 4095;
    const int row = gp >> 6, col = gp & 63;
    const int rq  = row >> 2, w = row & 3;

    const float* p0 = P + ((size_t)((b << 5) | (rq << 1)) << 12) + (w << 10) + (col << 4);
    const float* p1 = p0 + (1 << 12);
    float v[9];
#pragma unroll
    for (int c = 0; c < 9; ++c) v[c] = p0[c] + p1[c];

    if (b == 0) {
        out[2 * gp]     = -3.0f + (float)row * STEP;
        out[2 * gp + 1] = -3.0f + (float)col * STEP;
    }
    float* o = out + 8192 + (size_t)t * 9;
    const float inv = 1.0f / (v[0] + 1e-6f);
    o[0] = v[0];
#pragma unroll
    for (int c = 1; c < 9; ++c) o[c] = v[c] * inv;
}

extern "C" void kernel_launch(void* const* d_in, const int* in_sizes, int n_in,
                              void* d_out, int out_size, void* d_ws, size_t ws_size,
                              hipStream_t stream) {
    const float* X = (const float*)d_in[0];   // (16,1024,2) fp32
    const float* Y = (const float*)d_in[1];   // (16,1024,8) fp32
    float* out = (float*)d_out;

    _Float16* ExT = (_Float16*)d_ws;
    _Float16* EyT = ExT + (1 << 20);
    _Float16* YbT = EyT + (1 << 20);
    float*    P   = (float*)((char*)d_ws + (8u << 20));

    rkhs_tables<<<dim3(1152), dim3(256), 0, stream>>>(X, Y, ExT, EyT, YbT);
    rkhs_gemm  <<<dim3(512),  dim3(256), 0, stream>>>(ExT, EyT, YbT, P);
    rkhs_final <<<dim3(256),  dim3(256), 0, stream>>>(P, out);
}

// Round 9
// 69.309 us; speedup vs baseline: 1.2734x; 1.1153x over previous
//
#include <hip/hip_runtime.h>

typedef _Float16 half8   __attribute__((ext_vector_type(8)));
typedef float    floatx4 __attribute__((ext_vector_type(4)));

#define STEP  (6.0f / 63.0f)
#define SCAL  1.69864636f     // sqrt(2*log2(e)):  exp(-2 d^2) = 2^(-(S d)^2)

// All tables stored in MFMA fragment order (f16), so hot-loop reads are
// lane-contiguous 16B global loads (perfectly coalesced, L2-resident).
//   EyF [b][s:32][ct:4][l:64][j:8]  : Ey[col=ct*16+(l&15)][k=s*32+(l>>4)*8+j]
//   ExF [b][s:32][r:64][32]         : Ex[row r][k=s*32+0..31]
//   YbF [b][s:32][l:64][j:8]        : Yb^T[ch=l&15][k=s*32+(l>>4)*8+j]
#define EYF_SZ (16 * 65536)
#define EXF_SZ (16 * 65536)
#define YBF_SZ (16 * 16384)

// ---------------- Kernel 1: f16 tables in fragment order ----------------
__global__ __launch_bounds__(256) void rkhs_tables(
    const float* __restrict__ X, const float* __restrict__ Y,
    _Float16* __restrict__ EyF, _Float16* __restrict__ ExF,
    _Float16* __restrict__ YbF)
{
    const int gid = blockIdx.x * 256 + threadIdx.x;     // 0..294911
    if (gid < 131072) {                                 // EyF units
        const int n = gid & 15, q = (gid >> 4) & 3, ct = (gid >> 6) & 3,
                  s = (gid >> 8) & 31, b = gid >> 13;
        const int col = ct * 16 + n, k0 = s * 32 + q * 8;
        const float gS = SCAL * (-3.0f + (float)col * STEP);
        half8 h;
#pragma unroll
        for (int j = 0; j < 8; ++j) {
            const float x = X[(((b << 10) + k0 + j) << 1) + 1];
            const float d = fmaf(-SCAL, x, gS);
            h[j] = (_Float16)__builtin_amdgcn_exp2f(-(d * d));
        }
        *(half8*)(EyF + (size_t)gid * 8) = h;
    } else if (gid < 262144) {                          // ExF units
        const int u = gid - 131072;
        const int qq = u & 3, r = (u >> 2) & 63, s = (u >> 8) & 31, b = u >> 13;
        const int k0 = s * 32 + qq * 8;
        const float gS = SCAL * (-3.0f + (float)r * STEP);
        half8 h;
#pragma unroll
        for (int j = 0; j < 8; ++j) {
            const float x = X[(((b << 10) + k0 + j) << 1)];
            const float d = fmaf(-SCAL, x, gS);
            h[j] = (_Float16)__builtin_amdgcn_exp2f(-(d * d));
        }
        *(half8*)(ExF + (size_t)u * 8) = h;
    } else {                                            // YbF units
        const int v = gid - 262144;
        const int n = v & 15, q = (v >> 4) & 3, s = (v >> 6) & 31, b = v >> 11;
        const int k0 = s * 32 + q * 8;
        half8 h;
#pragma unroll
        for (int j = 0; j < 8; ++j) {
            float val = 0.f;
            if (n == 0)      val = 1.f;
            else if (n <= 8) val = Y[(((b << 10) + k0 + j) << 3) + n - 1];
            h[j] = (_Float16)val;
        }
        *(half8*)(YbF + (size_t)v * 8) = h;
    }
}

// ---------------- Kernel 2: L2-fed MFMA GEMM + fused epilogue ----------------
// 256 blocks = b(16) x rg(16: 4-row group); 512 thr = 8 waves = rp(2) x kq(4).
// Wave (rp,kq): rows rg*4+rp*2+{0,1}, all 64 cols (4 ct-tiles), k-quarter kq.
// B' = ex*yb folded into B: 8 MFMA per 7 global b128 loads, no LDS in hot loop.
__global__ __launch_bounds__(512, 2) void rkhs_gemm(
    const _Float16* __restrict__ EyF, const _Float16* __restrict__ ExF,
    const _Float16* __restrict__ YbF, float* __restrict__ out)
{
    __shared__ float2 red[3][2][16][64];   // 48 KB k-reduction parking

    const int b   = blockIdx.x >> 4;
    const int rg  = blockIdx.x & 15;
    const int tid = threadIdx.x;
    const int wv  = tid >> 6, l = tid & 63, q = l >> 4, n = l & 15;
    const int kq  = wv & 3, rp = wv >> 2;
    const int r0  = rg * 4 + rp * 2;

    floatx4 acc[2][4];
#pragma unroll
    for (int r = 0; r < 2; ++r)
#pragma unroll
        for (int ct = 0; ct < 4; ++ct) acc[r][ct] = (floatx4){0.f, 0.f, 0.f, 0.f};

#pragma unroll
    for (int ss = 0; ss < 8; ++ss) {
        const int s = kq * 8 + ss;
        const size_t sb = (size_t)(b * 32 + s);
        const half8 yb  = *(const half8*)(YbF + (sb * 64 + l) * 8);
        const half8 ex0 = *(const half8*)(ExF + (sb * 64 + r0) * 32 + q * 8);
        const half8 ex1 = *(const half8*)(ExF + (sb * 64 + r0 + 1) * 32 + q * 8);
        const half8 bp0 = ex0 * yb;        // 4x v_pk_mul_f16
        const half8 bp1 = ex1 * yb;
#pragma unroll
        for (int ct = 0; ct < 4; ++ct) {
            const half8 ey = *(const half8*)(EyF + ((sb * 4 + ct) * 64 + l) * 8);
            acc[0][ct] = __builtin_amdgcn_mfma_f32_16x16x32_f16(ey, bp0, acc[0][ct], 0, 0, 0);
            acc[1][ct] = __builtin_amdgcn_mfma_f32_16x16x32_f16(ey, bp1, acc[1][ct], 0, 0, 0);
        }
    }

    // ---- park partials (kq 1..3), float2 lane-stride-8B -> conflict-free ----
    if (kq != 0) {
#pragma unroll
        for (int r = 0; r < 2; ++r)
#pragma unroll
            for (int ct = 0; ct < 4; ++ct)
#pragma unroll
                for (int h = 0; h < 2; ++h)
                    red[kq - 1][rp][(r * 4 + ct) * 2 + h][l] =
                        make_float2(acc[r][ct][2 * h], acc[r][ct][2 * h + 1]);
    }
    __syncthreads();

    if (b == 0) {     // grid coords: 512 floats for this block's 4 rows
        const int p = tid >> 1;
        const int row = rg * 4 + (p >> 6), col = p & 63;
        out[(size_t)rg * 512 + tid] =
            (tid & 1) ? (-3.0f + (float)col * STEP) : (-3.0f + (float)row * STEP);
    }

    if (kq == 0) {
        // absorb the 3 parked k-quarters
#pragma unroll
        for (int t = 0; t < 3; ++t)
#pragma unroll
            for (int r = 0; r < 2; ++r)
#pragma unroll
                for (int ct = 0; ct < 4; ++ct)
#pragma unroll
                    for (int h = 0; h < 2; ++h) {
                        const float2 v = red[t][rp][(r * 4 + ct) * 2 + h][l];
                        acc[r][ct][2 * h]     += v.x;
                        acc[r][ct][2 * h + 1] += v.y;
                    }
        // finalize: density broadcast via shfl from the n==0 lane of each quad
#pragma unroll
        for (int r = 0; r < 2; ++r) {
            const int row = r0 + r;
#pragma unroll
            for (int ct = 0; ct < 4; ++ct)
#pragma unroll
                for (int i = 0; i < 4; ++i) {
                    const float dv  = __shfl(acc[r][ct][i], l & 48);   // lane (q,0)
                    const float inv = __builtin_amdgcn_rcpf(dv + 1e-6f);
                    if (n < 9) {
                        const int m = row * 64 + ct * 16 + q * 4 + i;
                        const float v = acc[r][ct][i];
                        out[8192 + ((size_t)(b << 12) + m) * 9 + n] = n ? v * inv : v;
                    }
                }
        }
    }
}

extern "C" void kernel_launch(void* const* d_in, const int* in_sizes, int n_in,
                              void* d_out, int out_size, void* d_ws, size_t ws_size,
                              hipStream_t stream) {
    const float* X = (const float*)d_in[0];   // (16,1024,2) fp32
    const float* Y = (const float*)d_in[1];   // (16,1024,8) fp32
    float* out = (float*)d_out;

    _Float16* EyF = (_Float16*)d_ws;
    _Float16* ExF = EyF + EYF_SZ;
    _Float16* YbF = ExF + EXF_SZ;

    rkhs_tables<<<dim3(1152), dim3(256), 0, stream>>>(X, Y, EyF, ExF, YbF);
    rkhs_gemm  <<<dim3(256),  dim3(512), 0, stream>>>(EyF, ExF, YbF, out);
}

// Round 10
// 67.583 us; speedup vs baseline: 1.3059x; 1.0255x over previous
//
#include <hip/hip_runtime.h>

typedef _Float16 half8   __attribute__((ext_vector_type(8)));
typedef float    floatx4 __attribute__((ext_vector_type(4)));

#define STEP  (6.0f / 63.0f)
#define SCAL  1.69864636f     // sqrt(2*log2(e)):  exp(-2 d^2) = 2^(-(S d)^2)

// Tables in MFMA fragment order (f16) — hot-loop reads are lane-contiguous
// 16B global loads (coalesced, L2-resident).
//   EyF [b][s:32][ct:4][l:64][j:8] : Ey[col=ct*16+(l&15)][k=s*32+(l>>4)*8+j]
//   ExF [b][s:32][r:64][32]        : Ex[row r][k=s*32+0..31]
//   YbF [b][s:32][l:64][j:8]       : Yb^T[ch=l&15][k=s*32+(l>>4)*8+j]
#define EYF_SZ (16 * 65536)
#define EXF_SZ (16 * 65536)
#define YBF_SZ (16 * 16384)

// ---------------- Kernel 1: f16 tables in fragment order ----------------
__global__ __launch_bounds__(256) void rkhs_tables(
    const float* __restrict__ X, const float* __restrict__ Y,
    _Float16* __restrict__ EyF, _Float16* __restrict__ ExF,
    _Float16* __restrict__ YbF)
{
    const int gid = blockIdx.x * 256 + threadIdx.x;     // 0..294911
    if (gid < 131072) {                                 // EyF units
        const int n = gid & 15, q = (gid >> 4) & 3, ct = (gid >> 6) & 3,
                  s = (gid >> 8) & 31, b = gid >> 13;
        const int col = ct * 16 + n, k0 = s * 32 + q * 8;
        const float gS = SCAL * (-3.0f + (float)col * STEP);
        half8 h;
#pragma unroll
        for (int j = 0; j < 8; ++j) {
            const float x = X[(((b << 10) + k0 + j) << 1) + 1];
            const float d = fmaf(-SCAL, x, gS);
            h[j] = (_Float16)__builtin_amdgcn_exp2f(-(d * d));
        }
        *(half8*)(EyF + (size_t)gid * 8) = h;
    } else if (gid < 262144) {                          // ExF units
        const int u = gid - 131072;
        const int qq = u & 3, r = (u >> 2) & 63, s = (u >> 8) & 31, b = u >> 13;
        const int k0 = s * 32 + qq * 8;
        const float gS = SCAL * (-3.0f + (float)r * STEP);
        half8 h;
#pragma unroll
        for (int j = 0; j < 8; ++j) {
            const float x = X[(((b << 10) + k0 + j) << 1)];
            const float d = fmaf(-SCAL, x, gS);
            h[j] = (_Float16)__builtin_amdgcn_exp2f(-(d * d));
        }
        *(half8*)(ExF + (size_t)u * 8) = h;
    } else {                                            // YbF units
        const int v = gid - 262144;
        const int n = v & 15, q = (v >> 4) & 3, s = (v >> 6) & 31, b = v >> 11;
        const int k0 = s * 32 + q * 8;
        half8 h;
#pragma unroll
        for (int j = 0; j < 8; ++j) {
            float val = 0.f;
            if (n == 0)      val = 1.f;
            else if (n <= 8) val = Y[(((b << 10) + k0 + j) << 3) + n - 1];
            h[j] = (_Float16)val;
        }
        *(half8*)(YbF + (size_t)v * 8) = h;
    }
}

// ---------------- Kernel 2: MFMA GEMM, in-block k-reduction ----------------
// 256 blocks = b(16) x rw(16: 4-row group); 512 thr = 8 waves = 8 kq.
// Every wave: same 4 rows, all 64 cols (4 ct), k-eighth (4 s-chunks).
// Per iter: yb 1 + ex 4 (16-lane-shared) + ey 4 loads -> 16 pk_mul + 16 MFMA.
// k-reduction: 3-round LDS tree (float4 lane-contiguous, conflict-free),
// then fused normalize + coalesced contiguous store. No partials buffer.
__global__ __launch_bounds__(512, 2) void rkhs_gemm(
    const _Float16* __restrict__ EyF, const _Float16* __restrict__ ExF,
    const _Float16* __restrict__ YbF, float* __restrict__ out)
{
    __shared__ floatx4 spark[4096];     // 64 KB: 4 slots x 1024 float4
    float* sfin = (float*)spark;        // reused for the final [256 m][9] tile

    const int b   = blockIdx.x >> 4;
    const int rw  = blockIdx.x & 15;
    const int tid = threadIdx.x;
    const int kq  = tid >> 6, l = tid & 63, q = l >> 4, n = l & 15;
    const int r0  = rw * 4;

    // grid coords output (independent; b==0 blocks, 512 floats each)
    if (b == 0) {
        const int row = r0 + (tid >> 7), rem = tid & 127;
        out[(size_t)rw * 512 + tid] = (rem & 1)
            ? (-3.0f + (float)(rem >> 1) * STEP)
            : (-3.0f + (float)row * STEP);
    }

    floatx4 acc[4][4];                  // [rr][ct]
#pragma unroll
    for (int rr = 0; rr < 4; ++rr)
#pragma unroll
        for (int ct = 0; ct < 4; ++ct) acc[rr][ct] = (floatx4){0.f, 0.f, 0.f, 0.f};

#pragma unroll
    for (int ss = 0; ss < 4; ++ss) {
        const int s = kq * 4 + ss;
        const size_t sb = (size_t)(b * 32 + s);
        const half8 yb = *(const half8*)(YbF + (sb * 64 + l) * 8);
        half8 bp[4];
#pragma unroll
        for (int rr = 0; rr < 4; ++rr) {
            const half8 ex = *(const half8*)(ExF + (sb * 64 + r0 + rr) * 32 + q * 8);
            bp[rr] = ex * yb;           // 4x v_pk_mul_f16
        }
#pragma unroll
        for (int ct = 0; ct < 4; ++ct) {
            const half8 ey = *(const half8*)(EyF + ((sb * 4 + ct) * 64 + l) * 8);
#pragma unroll
            for (int rr = 0; rr < 4; ++rr)
                acc[rr][ct] = __builtin_amdgcn_mfma_f32_16x16x32_f16(ey, bp[rr], acc[rr][ct], 0, 0, 0);
        }
    }

    // ---- 3-round tree reduction over kq (lane-contiguous float4) ----
#define PARKA(slot)                                                        \
    { _Pragma("unroll") for (int rr = 0; rr < 4; ++rr)                     \
      _Pragma("unroll") for (int ct = 0; ct < 4; ++ct)                     \
          spark[(slot) * 1024 + (rr * 4 + ct) * 64 + l] = acc[rr][ct]; }
#define ABSORBA(slot)                                                      \
    { _Pragma("unroll") for (int rr = 0; rr < 4; ++rr)                     \
      _Pragma("unroll") for (int ct = 0; ct < 4; ++ct)                     \
          acc[rr][ct] += spark[(slot) * 1024 + (rr * 4 + ct) * 64 + l]; }

    if (kq >= 4) PARKA(kq - 4)
    __syncthreads();
    if (kq < 4)  ABSORBA(kq)
    __syncthreads();
    if (kq == 2 || kq == 3) PARKA(kq - 2)
    __syncthreads();
    if (kq < 2)  ABSORBA(kq)
    __syncthreads();
    if (kq == 1) PARKA(0)
    __syncthreads();

    if (kq == 0) {
        ABSORBA(0)
        // write the reduced tile into LDS as [m-within-block 256][9]
#pragma unroll
        for (int rr = 0; rr < 4; ++rr)
#pragma unroll
            for (int ct = 0; ct < 4; ++ct)
                if (n < 9)
#pragma unroll
                    for (int i = 0; i < 4; ++i)
                        sfin[(rr * 64 + ct * 16 + q * 4 + i) * 9 + n] = acc[rr][ct][i];
    }
#undef PARKA
#undef ABSORBA
    __syncthreads();

    // ---- fused normalize + coalesced store (2304 contiguous floats) ----
    const size_t obase = 8192 + ((size_t)b * 4096 + (size_t)r0 * 64) * 9;
#pragma unroll
    for (int it = 0; it < 5; ++it) {
        const int idx = it * 512 + tid;
        if (idx < 2304) {
            const int m  = idx / 9;
            const int ch = idx - m * 9;
            const float dens = sfin[m * 9];
            const float v    = sfin[idx];
            out[obase + idx] = ch ? v * __builtin_amdgcn_rcpf(dens + 1e-6f) : dens;
        }
    }
}

extern "C" void kernel_launch(void* const* d_in, const int* in_sizes, int n_in,
                              void* d_out, int out_size, void* d_ws, size_t ws_size,
                              hipStream_t stream) {
    const float* X = (const float*)d_in[0];   // (16,1024,2) fp32
    const float* Y = (const float*)d_in[1];   // (16,1024,8) fp32
    float* out = (float*)d_out;

    _Float16* EyF = (_Float16*)d_ws;
    _Float16* ExF = EyF + EYF_SZ;
    _Float16* YbF = ExF + EXF_SZ;

    rkhs_tables<<<dim3(1152), dim3(256), 0, stream>>>(X, Y, EyF, ExF, YbF);
    rkhs_gemm  <<<dim3(256),  dim3(512), 0, stream>>>(EyF, ExF, YbF, out);
}